// Round 3
// baseline (1262.557 us; speedup 1.0000x reference)
//
#include <hip/hip_runtime.h>
#include <math.h>

// ReAttention: B=8, N=1024, C=768, H=8, d=96, s=16.
// d_out = [ out (8*1024*768) | attn_postBN (8*8*1024*1024) ]
// ws    = [ q | k | v | o5 (attn@V, B,N,C) | partial(16*8192) | stats(32) ] floats

#define NB    8
#define NN    1024
#define NC    768
#define NH    8
#define ND    96
#define BN_EPS 1e-5f

// ---------------------------------------------------------------- conv (q,k,v)
__global__ __launch_bounds__(256) void k_conv(const float* __restrict__ x,
    const float* __restrict__ wq, const float* __restrict__ wk,
    const float* __restrict__ wv,
    float* __restrict__ q, float* __restrict__ k, float* __restrict__ v)
{
    const int token = blockIdx.x;          // b*N+n, 8192 blocks
    const int t = threadIdx.x;             // 256 = one pixel each
    __shared__ float img[768];
    __shared__ float wsm[3][81];
    const float* xb = x + (size_t)token * 768;
    for (int i = t; i < 768; i += 256) img[i] = xb[i];
    if (t < 81) { wsm[0][t] = wq[t]; wsm[1][t] = wk[t]; wsm[2][t] = wv[t]; }
    __syncthreads();
    const int r = t >> 4, c = t & 15;
    float* outs[3] = { q, k, v };
    for (int cv = 0; cv < 3; ++cv) {
        for (int o = 0; o < 3; ++o) {
            float acc = 0.f;
            for (int i = 0; i < 3; ++i)
                for (int dr = 0; dr < 3; ++dr) {
                    int rr = r + dr - 1;
                    if (rr < 0 || rr > 15) continue;
                    for (int dc = 0; dc < 3; ++dc) {
                        int cc = c + dc - 1;
                        if (cc < 0 || cc > 15) continue;
                        acc = fmaf(img[i*256 + rr*16 + cc],
                                   wsm[cv][(o*3 + i)*9 + dr*3 + dc], acc);
                    }
                }
            outs[cv][(size_t)token*768 + o*256 + t] = acc;
        }
    }
}

// ---------------------------------------------------------------- Q K^T logits
// grid (16 mtile, 16 ntile, 64 bh); 64x64 C-tile, K=96; writes scaled logits.
__global__ __launch_bounds__(256) void k_qk(const float* __restrict__ q,
    const float* __restrict__ k, float* __restrict__ s_out)
{
    const int mt = blockIdx.x, nt = blockIdx.y, bh = blockIdx.z;
    const int b = bh >> 3, h = bh & 7;
    const int t = threadIdx.x;
    const int tx = t & 15, ty = t >> 4;
    __shared__ float Qs[64][97];
    __shared__ float Ks[64][97];
    const int n0 = nt * 64, m0 = mt * 64;
    const float* qb = q + ((size_t)b*NN + n0)*NC + h*ND;
    const float* kb = k + ((size_t)b*NN + m0)*NC + h*ND;
    for (int j = 0; j < 6; ++j) {               // 1536 float4 per matrix
        int idx4 = t + 256*j;
        int row = idx4 / 24, c4 = idx4 - row*24;
        float4 qv = *reinterpret_cast<const float4*>(qb + (size_t)row*NC + c4*4);
        float4 kv = *reinterpret_cast<const float4*>(kb + (size_t)row*NC + c4*4);
        Qs[row][c4*4+0] = qv.x; Qs[row][c4*4+1] = qv.y;
        Qs[row][c4*4+2] = qv.z; Qs[row][c4*4+3] = qv.w;
        Ks[row][c4*4+0] = kv.x; Ks[row][c4*4+1] = kv.y;
        Ks[row][c4*4+2] = kv.z; Ks[row][c4*4+3] = kv.w;
    }
    __syncthreads();
    float acc[4][4];
    for (int i = 0; i < 4; ++i) for (int j = 0; j < 4; ++j) acc[i][j] = 0.f;
    for (int kk = 0; kk < 96; ++kk) {
        float a0 = Qs[ty][kk],    a1 = Qs[ty+16][kk];
        float a2 = Qs[ty+32][kk], a3 = Qs[ty+48][kk];
        float b0 = Ks[tx][kk],    b1 = Ks[tx+16][kk];
        float b2 = Ks[tx+32][kk], b3 = Ks[tx+48][kk];
        acc[0][0]=fmaf(a0,b0,acc[0][0]); acc[0][1]=fmaf(a0,b1,acc[0][1]);
        acc[0][2]=fmaf(a0,b2,acc[0][2]); acc[0][3]=fmaf(a0,b3,acc[0][3]);
        acc[1][0]=fmaf(a1,b0,acc[1][0]); acc[1][1]=fmaf(a1,b1,acc[1][1]);
        acc[1][2]=fmaf(a1,b2,acc[1][2]); acc[1][3]=fmaf(a1,b3,acc[1][3]);
        acc[2][0]=fmaf(a2,b0,acc[2][0]); acc[2][1]=fmaf(a2,b1,acc[2][1]);
        acc[2][2]=fmaf(a2,b2,acc[2][2]); acc[2][3]=fmaf(a2,b3,acc[2][3]);
        acc[3][0]=fmaf(a3,b0,acc[3][0]); acc[3][1]=fmaf(a3,b1,acc[3][1]);
        acc[3][2]=fmaf(a3,b2,acc[3][2]); acc[3][3]=fmaf(a3,b3,acc[3][3]);
    }
    const float scale = rsqrtf(96.0f);
    float* srow = s_out + ((size_t)bh*NN + n0)*NN + m0;
    for (int i = 0; i < 4; ++i)
        for (int j = 0; j < 4; ++j)
            srow[(size_t)(ty + 16*i)*NN + tx + 16*j] = acc[i][j] * scale;
}

// ------------------------------------------------- softmax + head-mix in place
// block per (b,n). Per-wave softmax (wave w owns heads 2w,2w+1 — no block
// barriers inside softmax), then head-mix with W[g,h], write mixed (pre-BN)
// rows back in place, emit BN partial sums (no atomics).
__global__ __launch_bounds__(256) void k_softmix(float* __restrict__ attn,
    const float* __restrict__ wmix_g, const float* __restrict__ bias_g,
    float* __restrict__ partial)
{
    const int bn = blockIdx.x;
    const int b = bn >> 10, n = bn & 1023;
    const int t = threadIdx.x, lane = t & 63, wid = t >> 6;
    __shared__ __align__(16) float row[8][1024];
    __shared__ float wmix[64];
    __shared__ float bsh[8];
    __shared__ float redsum[32], redsq[32];

    if (t < 64) wmix[t] = wmix_g[t];
    if (t >= 64 && t < 72) bsh[t - 64] = bias_g[t - 64];
    for (int h = 0; h < 8; ++h) {
        const float4* src = reinterpret_cast<const float4*>(
            attn + (((size_t)b*8 + h)*NN + n)*NN);
        reinterpret_cast<float4*>(row[h])[t] = src[t];
    }
    __syncthreads();

    // wave-local softmax: wave `wid` owns heads 2*wid and 2*wid+1
    for (int hh = 0; hh < 2; ++hh) {
        const int h = wid * 2 + hh;
        float vals[16];
        float lm = -1e30f;
        #pragma unroll
        for (int j = 0; j < 16; ++j) {
            vals[j] = row[h][lane + 64*j];
            lm = fmaxf(lm, vals[j]);
        }
        #pragma unroll
        for (int off = 32; off > 0; off >>= 1)
            lm = fmaxf(lm, __shfl_xor(lm, off));
        float ls = 0.f;
        #pragma unroll
        for (int j = 0; j < 16; ++j) {
            float e = __expf(vals[j] - lm);
            vals[j] = e;
            ls += e;
        }
        #pragma unroll
        for (int off = 32; off > 0; off >>= 1)
            ls += __shfl_xor(ls, off);
        const float inv = 1.f / ls;
        #pragma unroll
        for (int j = 0; j < 16; ++j)
            row[h][lane + 64*j] = vals[j] * inv;
    }
    __syncthreads();

    float sum_l[8], sq_l[8];
    for (int g = 0; g < 8; ++g) { sum_l[g] = 0.f; sq_l[g] = 0.f; }
    for (int mc = 0; mc < 4; ++mc) {
        int m = mc*256 + t;
        float a[8];
        for (int h = 0; h < 8; ++h) a[h] = row[h][m];
        for (int g = 0; g < 8; ++g) {
            float mix = bsh[g];
            for (int h = 0; h < 8; ++h) mix = fmaf(wmix[g*8 + h], a[h], mix);
            attn[(((size_t)b*8 + g)*NN + n)*NN + m] = mix;
            sum_l[g] += mix;
            sq_l[g] = fmaf(mix, mix, sq_l[g]);
        }
    }
    for (int g = 0; g < 8; ++g) {
        float s = sum_l[g], s2 = sq_l[g];
        for (int off = 32; off > 0; off >>= 1) {
            s  += __shfl_down(s,  off);
            s2 += __shfl_down(s2, off);
        }
        if (lane == 0) { redsum[g*4 + wid] = s; redsq[g*4 + wid] = s2; }
    }
    __syncthreads();
    if (t < 8) {
        partial[(size_t)t*8192 + bn] =
            redsum[t*4] + redsum[t*4+1] + redsum[t*4+2] + redsum[t*4+3];
        partial[(size_t)(8 + t)*8192 + bn] =
            redsq[t*4] + redsq[t*4+1] + redsq[t*4+2] + redsq[t*4+3];
    }
}

// ------------------------------------------------------------- BN scale/shift
__global__ __launch_bounds__(256) void k_bnprep(const float* __restrict__ partial,
    const float* __restrict__ gamma, const float* __restrict__ beta,
    float* __restrict__ stats)
{
    const int t = threadIdx.x, lane = t & 63, wid = t >> 6;
    __shared__ float tot[16];
    __shared__ float red[4];
    for (int g = 0; g < 16; ++g) {
        float s = 0.f;
        for (int j = 0; j < 32; ++j) s += partial[(size_t)g*8192 + t + 256*j];
        for (int off = 32; off > 0; off >>= 1) s += __shfl_down(s, off);
        if (lane == 0) red[wid] = s;
        __syncthreads();
        if (t == 0) tot[g] = red[0] + red[1] + red[2] + red[3];
        __syncthreads();
    }
    if (t < 8) {
        const float count = 8388608.0f;   // B*N*N
        float mean = tot[t] / count;
        float var = tot[8 + t] / count - mean * mean;   // biased
        float sc = gamma[t] * rsqrtf(var + BN_EPS);
        stats[16 + t] = sc;
        stats[24 + t] = beta[t] - mean * sc;
    }
}

// ---------------------------------------------------- BN apply (streaming RMW)
// In-place affine over attn. Load/store ADJACENT (same line, same instruction
// neighborhood) — keeps the RMW write-combining in L2 (R2 lesson). No LDS,
// high occupancy. grid 8192 = 64 (b,h) planes x 128 chunks.
__global__ __launch_bounds__(256) void k_bnapply(float* __restrict__ attn,
    const float* __restrict__ stats)
{
    const int plane = blockIdx.x >> 7;         // b*8 + h
    const int chunk = blockIdx.x & 127;
    const int h = plane & 7;
    const float sc = stats[16 + h], sh = stats[24 + h];
    float4* p = reinterpret_cast<float4*>(attn + (size_t)plane*NN*NN)
              + (size_t)chunk*2048 + threadIdx.x;
    #pragma unroll
    for (int j = 0; j < 8; ++j) {
        float4 a = p[(size_t)j*256];
        a.x = fmaf(a.x, sc, sh); a.y = fmaf(a.y, sc, sh);
        a.z = fmaf(a.z, sc, sh); a.w = fmaf(a.w, sc, sh);
        p[(size_t)j*256] = a;
    }
}

// --------------------------------------------------- attn(post-BN) @ V (lite)
// grid (16 ntile, 8 h, 8 b); Tn=64, Tm=64. attn is READ-ONLY here (BN already
// applied in place by k_bnapply), so register-prefetch pipelining is safe:
// prologue loads tile 0; each iter stages regs->LDS, barriers, issues next
// tile's global loads (latency hides under the 64-step FMA loop), computes.
__global__ __launch_bounds__(256) void k_attnv(const float* __restrict__ attn,
    const float* __restrict__ v, float* __restrict__ o)
{
    const int nt = blockIdx.x, h = blockIdx.y, b = blockIdx.z;
    const int t = threadIdx.x;
    const int l = t & 31, dg = t >> 5;
    __shared__ float As[64][65];     // pad 65: conflict-free column reads
    __shared__ float Vs[64][100];    // pad 100: float4-aligned rows
    const int n0 = nt * 64;
    const float* attn_b = attn + (((size_t)b*8 + h)*NN + n0)*NN;
    const float* v_b = v + (size_t)b*NN*NC + (size_t)h*ND;

    float4 a_reg[4], v_reg[6];

    // ---- prologue: prefetch tile 0 into registers
    #pragma unroll
    for (int j = 0; j < 4; ++j) {
        int idx4 = t + 256*j;
        int row = idx4 >> 4, c4 = idx4 & 15;
        a_reg[j] = *reinterpret_cast<const float4*>(
            attn_b + (size_t)row*NN + c4*4);
    }
    #pragma unroll
    for (int j = 0; j < 6; ++j) {
        int idx4 = t + 256*j;
        int row = idx4 / 24, c4 = idx4 - row*24;
        v_reg[j] = *reinterpret_cast<const float4*>(
            v_b + (size_t)row*NC + c4*4);
    }

    float acc0[12], acc1[12];
    #pragma unroll
    for (int j = 0; j < 12; ++j) { acc0[j] = 0.f; acc1[j] = 0.f; }

    for (int it = 0; it < 16; ++it) {
        const int m0 = it * 64;
        // ---- stage regs -> LDS
        #pragma unroll
        for (int j = 0; j < 4; ++j) {
            int idx4 = t + 256*j;
            int row = idx4 >> 4, c4 = idx4 & 15;
            As[row][c4*4+0] = a_reg[j].x; As[row][c4*4+1] = a_reg[j].y;
            As[row][c4*4+2] = a_reg[j].z; As[row][c4*4+3] = a_reg[j].w;
        }
        #pragma unroll
        for (int j = 0; j < 6; ++j) {
            int idx4 = t + 256*j;
            int row = idx4 / 24, c4 = idx4 - row*24;
            *reinterpret_cast<float4*>(&Vs[row][c4*4]) = v_reg[j];
        }
        __syncthreads();
        // ---- issue next tile's global loads (latency hides under compute)
        if (it + 1 < 16) {
            const int m1 = m0 + 64;
            #pragma unroll
            for (int j = 0; j < 4; ++j) {
                int idx4 = t + 256*j;
                int row = idx4 >> 4, c4 = idx4 & 15;
                a_reg[j] = *reinterpret_cast<const float4*>(
                    attn_b + (size_t)row*NN + m1 + c4*4);
            }
            #pragma unroll
            for (int j = 0; j < 6; ++j) {
                int idx4 = t + 256*j;
                int row = idx4 / 24, c4 = idx4 - row*24;
                v_reg[j] = *reinterpret_cast<const float4*>(
                    v_b + (size_t)(m1 + row)*NC + c4*4);
            }
        }
        // ---- compute tile it
        #pragma unroll 8
        for (int mi = 0; mi < 64; ++mi) {
            float4 v0 = *reinterpret_cast<const float4*>(&Vs[mi][dg*12]);
            float4 v1 = *reinterpret_cast<const float4*>(&Vs[mi][dg*12 + 4]);
            float4 v2 = *reinterpret_cast<const float4*>(&Vs[mi][dg*12 + 8]);
            float a0 = As[l][mi], a1 = As[l + 32][mi];
            acc0[0]=fmaf(a0,v0.x,acc0[0]); acc0[1]=fmaf(a0,v0.y,acc0[1]);
            acc0[2]=fmaf(a0,v0.z,acc0[2]); acc0[3]=fmaf(a0,v0.w,acc0[3]);
            acc0[4]=fmaf(a0,v1.x,acc0[4]); acc0[5]=fmaf(a0,v1.y,acc0[5]);
            acc0[6]=fmaf(a0,v1.z,acc0[6]); acc0[7]=fmaf(a0,v1.w,acc0[7]);
            acc0[8]=fmaf(a0,v2.x,acc0[8]); acc0[9]=fmaf(a0,v2.y,acc0[9]);
            acc0[10]=fmaf(a0,v2.z,acc0[10]); acc0[11]=fmaf(a0,v2.w,acc0[11]);
            acc1[0]=fmaf(a1,v0.x,acc1[0]); acc1[1]=fmaf(a1,v0.y,acc1[1]);
            acc1[2]=fmaf(a1,v0.z,acc1[2]); acc1[3]=fmaf(a1,v0.w,acc1[3]);
            acc1[4]=fmaf(a1,v1.x,acc1[4]); acc1[5]=fmaf(a1,v1.y,acc1[5]);
            acc1[6]=fmaf(a1,v1.z,acc1[6]); acc1[7]=fmaf(a1,v1.w,acc1[7]);
            acc1[8]=fmaf(a1,v2.x,acc1[8]); acc1[9]=fmaf(a1,v2.y,acc1[9]);
            acc1[10]=fmaf(a1,v2.z,acc1[10]); acc1[11]=fmaf(a1,v2.w,acc1[11]);
        }
        __syncthreads();
    }
    // write out rows n0+l and n0+l+32, d-range dg*12..dg*12+11
    {
        float* orow0 = o + ((size_t)b*NN + n0 + l)*NC + (size_t)h*ND + dg*12;
        float* orow1 = o + ((size_t)b*NN + n0 + l + 32)*NC + (size_t)h*ND + dg*12;
        *reinterpret_cast<float4*>(orow0+0) = make_float4(acc0[0],acc0[1],acc0[2],acc0[3]);
        *reinterpret_cast<float4*>(orow0+4) = make_float4(acc0[4],acc0[5],acc0[6],acc0[7]);
        *reinterpret_cast<float4*>(orow0+8) = make_float4(acc0[8],acc0[9],acc0[10],acc0[11]);
        *reinterpret_cast<float4*>(orow1+0) = make_float4(acc1[0],acc1[1],acc1[2],acc1[3]);
        *reinterpret_cast<float4*>(orow1+4) = make_float4(acc1[4],acc1[5],acc1[6],acc1[7]);
        *reinterpret_cast<float4*>(orow1+8) = make_float4(acc1[8],acc1[9],acc1[10],acc1[11]);
    }
}

// --------------------------------------------------------------- final proj
// out2[r,c'] = sum_k a[r,k] * W[c',k] + b[c']
// 64x64 block tile, BK=64, 4x4 micro-tile/thread, float4 LDS fragment reads.
// grid (12 c'-tiles, 128 r-tiles), 256 threads.
#define PROJ_DOT(i,j,av,bv) \
    acc[i][j]=fmaf(av.x,bv.x,acc[i][j]); acc[i][j]=fmaf(av.y,bv.y,acc[i][j]); \
    acc[i][j]=fmaf(av.z,bv.z,acc[i][j]); acc[i][j]=fmaf(av.w,bv.w,acc[i][j]);

__global__ __launch_bounds__(256) void k_proj(const float* __restrict__ a,
    const float* __restrict__ w, const float* __restrict__ bias,
    float* __restrict__ out)
{
    const int ct = blockIdx.x, rt = blockIdx.y;
    const int t = threadIdx.x;
    const int tx = t & 15, ty = t >> 4;
    __shared__ float As[64][68];     // 68: float4-aligned pad, 2-way max conflict
    __shared__ float Ws[64][68];
    const int r0 = rt * 64, c0 = ct * 64;
    float acc[4][4];
    #pragma unroll
    for (int i = 0; i < 4; ++i)
        #pragma unroll
        for (int j = 0; j < 4; ++j) acc[i][j] = 0.f;

    for (int k0 = 0; k0 < 768; k0 += 64) {
        // stage A (64 rows x 64 k) and W (64 cols x 64 k); 4 float4 each
        #pragma unroll
        for (int j = 0; j < 4; ++j) {
            int idx4 = t + 256*j;
            int row = idx4 >> 4, c4 = idx4 & 15;
            float4 av = *reinterpret_cast<const float4*>(
                a + (size_t)(r0 + row)*NC + k0 + c4*4);
            float4 wv = *reinterpret_cast<const float4*>(
                w + (size_t)(c0 + row)*NC + k0 + c4*4);
            *reinterpret_cast<float4*>(&As[row][c4*4]) = av;
            *reinterpret_cast<float4*>(&Ws[row][c4*4]) = wv;
        }
        __syncthreads();
        #pragma unroll 4
        for (int kk = 0; kk < 64; kk += 4) {
            float4 a0 = *reinterpret_cast<const float4*>(&As[ty     ][kk]);
            float4 a1 = *reinterpret_cast<const float4*>(&As[ty + 16][kk]);
            float4 a2 = *reinterpret_cast<const float4*>(&As[ty + 32][kk]);
            float4 a3 = *reinterpret_cast<const float4*>(&As[ty + 48][kk]);
            float4 b0 = *reinterpret_cast<const float4*>(&Ws[tx     ][kk]);
            float4 b1 = *reinterpret_cast<const float4*>(&Ws[tx + 16][kk]);
            float4 b2 = *reinterpret_cast<const float4*>(&Ws[tx + 32][kk]);
            float4 b3 = *reinterpret_cast<const float4*>(&Ws[tx + 48][kk]);
            PROJ_DOT(0,0,a0,b0) PROJ_DOT(0,1,a0,b1) PROJ_DOT(0,2,a0,b2) PROJ_DOT(0,3,a0,b3)
            PROJ_DOT(1,0,a1,b0) PROJ_DOT(1,1,a1,b1) PROJ_DOT(1,2,a1,b2) PROJ_DOT(1,3,a1,b3)
            PROJ_DOT(2,0,a2,b0) PROJ_DOT(2,1,a2,b1) PROJ_DOT(2,2,a2,b2) PROJ_DOT(2,3,a2,b3)
            PROJ_DOT(3,0,a3,b0) PROJ_DOT(3,1,a3,b1) PROJ_DOT(3,2,a3,b2) PROJ_DOT(3,3,a3,b3)
        }
        __syncthreads();
    }
    #pragma unroll
    for (int i = 0; i < 4; ++i) {
        float* orow = out + (size_t)(r0 + ty + 16*i)*NC + c0;
        #pragma unroll
        for (int j = 0; j < 4; ++j)
            orow[tx + 16*j] = acc[i][j] + bias[c0 + tx + 16*j];
    }
}

// ------------------------------------------------------------------- launcher
extern "C" void kernel_launch(void* const* d_in, const int* in_sizes, int n_in,
                              void* d_out, int out_size, void* d_ws, size_t ws_size,
                              hipStream_t stream)
{
    const float* x     = (const float*)d_in[0];
    const float* wq    = (const float*)d_in[1];
    const float* wk    = (const float*)d_in[2];
    const float* wv    = (const float*)d_in[3];
    const float* rw    = (const float*)d_in[4];   // (H,H,1,1)
    const float* rb    = (const float*)d_in[5];
    const float* gamma = (const float*)d_in[6];
    const float* beta  = (const float*)d_in[7];
    const float* pw    = (const float*)d_in[8];
    const float* pb    = (const float*)d_in[9];

    float* out  = (float*)d_out;                  // 6,291,456
    float* attn = out + (size_t)NB*NN*NC;         // 67,108,864

    float* ws      = (float*)d_ws;
    float* q       = ws;
    float* k       = ws + (size_t) 6291456;
    float* v       = ws + (size_t)12582912;
    float* o5      = ws + (size_t)18874368;
    float* partial = ws + (size_t)25165824;       // 16*8192
    float* stats   = ws + (size_t)25296896;       // 32

    k_conv   <<<8192, 256, 0, stream>>>(x, wq, wk, wv, q, k, v);
    k_qk     <<<dim3(16, 16, 64), 256, 0, stream>>>(q, k, attn);
    k_softmix<<<8192, 256, 0, stream>>>(attn, rw, rb, partial);
    k_bnprep <<<1, 256, 0, stream>>>(partial, gamma, beta, stats);
    k_bnapply<<<8192, 256, 0, stream>>>(attn, stats);
    k_attnv  <<<dim3(16, 8, 8), 256, 0, stream>>>(attn, v, o5);
    k_proj   <<<dim3(12, 128), 256, 0, stream>>>(o5, pw, pb, out);
}

// Round 4
// 1126.662 us; speedup vs baseline: 1.1206x; 1.1206x over previous
//
#include <hip/hip_runtime.h>
#include <math.h>

// ReAttention: B=8, N=1024, C=768, H=8, d=96, s=16.
// d_out = [ out (8*1024*768) | attn_postBN (8*8*1024*1024) ]
// ws    = [ q | k | v | o5 (attn@V, B,N,C) | partial(16*8192) | stats(32) ] floats

#define NB    8
#define NN    1024
#define NC    768
#define NH    8
#define ND    96
#define BN_EPS 1e-5f

// ---------------------------------------------------------------- conv (q,k,v)
__global__ __launch_bounds__(256) void k_conv(const float* __restrict__ x,
    const float* __restrict__ wq, const float* __restrict__ wk,
    const float* __restrict__ wv,
    float* __restrict__ q, float* __restrict__ k, float* __restrict__ v)
{
    const int token = blockIdx.x;          // b*N+n, 8192 blocks
    const int t = threadIdx.x;             // 256 = one pixel each
    __shared__ float img[768];
    __shared__ float wsm[3][81];
    const float* xb = x + (size_t)token * 768;
    for (int i = t; i < 768; i += 256) img[i] = xb[i];
    if (t < 81) { wsm[0][t] = wq[t]; wsm[1][t] = wk[t]; wsm[2][t] = wv[t]; }
    __syncthreads();
    const int r = t >> 4, c = t & 15;
    float* outs[3] = { q, k, v };
    for (int cv = 0; cv < 3; ++cv) {
        for (int o = 0; o < 3; ++o) {
            float acc = 0.f;
            for (int i = 0; i < 3; ++i)
                for (int dr = 0; dr < 3; ++dr) {
                    int rr = r + dr - 1;
                    if (rr < 0 || rr > 15) continue;
                    for (int dc = 0; dc < 3; ++dc) {
                        int cc = c + dc - 1;
                        if (cc < 0 || cc > 15) continue;
                        acc = fmaf(img[i*256 + rr*16 + cc],
                                   wsm[cv][(o*3 + i)*9 + dr*3 + dc], acc);
                    }
                }
            outs[cv][(size_t)token*768 + o*256 + t] = acc;
        }
    }
}

// ---------------------------------------------------------------- Q K^T logits
// grid (16 mtile, 16 ntile, 64 bh); 64x64 C-tile, K=96; writes scaled logits.
__global__ __launch_bounds__(256) void k_qk(const float* __restrict__ q,
    const float* __restrict__ k, float* __restrict__ s_out)
{
    const int mt = blockIdx.x, nt = blockIdx.y, bh = blockIdx.z;
    const int b = bh >> 3, h = bh & 7;
    const int t = threadIdx.x;
    const int tx = t & 15, ty = t >> 4;
    __shared__ float Qs[64][97];
    __shared__ float Ks[64][97];
    const int n0 = nt * 64, m0 = mt * 64;
    const float* qb = q + ((size_t)b*NN + n0)*NC + h*ND;
    const float* kb = k + ((size_t)b*NN + m0)*NC + h*ND;
    for (int j = 0; j < 6; ++j) {               // 1536 float4 per matrix
        int idx4 = t + 256*j;
        int row = idx4 / 24, c4 = idx4 - row*24;
        float4 qv = *reinterpret_cast<const float4*>(qb + (size_t)row*NC + c4*4);
        float4 kv = *reinterpret_cast<const float4*>(kb + (size_t)row*NC + c4*4);
        Qs[row][c4*4+0] = qv.x; Qs[row][c4*4+1] = qv.y;
        Qs[row][c4*4+2] = qv.z; Qs[row][c4*4+3] = qv.w;
        Ks[row][c4*4+0] = kv.x; Ks[row][c4*4+1] = kv.y;
        Ks[row][c4*4+2] = kv.z; Ks[row][c4*4+3] = kv.w;
    }
    __syncthreads();
    float acc[4][4];
    for (int i = 0; i < 4; ++i) for (int j = 0; j < 4; ++j) acc[i][j] = 0.f;
    for (int kk = 0; kk < 96; ++kk) {
        float a0 = Qs[ty][kk],    a1 = Qs[ty+16][kk];
        float a2 = Qs[ty+32][kk], a3 = Qs[ty+48][kk];
        float b0 = Ks[tx][kk],    b1 = Ks[tx+16][kk];
        float b2 = Ks[tx+32][kk], b3 = Ks[tx+48][kk];
        acc[0][0]=fmaf(a0,b0,acc[0][0]); acc[0][1]=fmaf(a0,b1,acc[0][1]);
        acc[0][2]=fmaf(a0,b2,acc[0][2]); acc[0][3]=fmaf(a0,b3,acc[0][3]);
        acc[1][0]=fmaf(a1,b0,acc[1][0]); acc[1][1]=fmaf(a1,b1,acc[1][1]);
        acc[1][2]=fmaf(a1,b2,acc[1][2]); acc[1][3]=fmaf(a1,b3,acc[1][3]);
        acc[2][0]=fmaf(a2,b0,acc[2][0]); acc[2][1]=fmaf(a2,b1,acc[2][1]);
        acc[2][2]=fmaf(a2,b2,acc[2][2]); acc[2][3]=fmaf(a2,b3,acc[2][3]);
        acc[3][0]=fmaf(a3,b0,acc[3][0]); acc[3][1]=fmaf(a3,b1,acc[3][1]);
        acc[3][2]=fmaf(a3,b2,acc[3][2]); acc[3][3]=fmaf(a3,b3,acc[3][3]);
    }
    const float scale = rsqrtf(96.0f);
    float* srow = s_out + ((size_t)bh*NN + n0)*NN + m0;
    for (int i = 0; i < 4; ++i)
        for (int j = 0; j < 4; ++j)
            srow[(size_t)(ty + 16*i)*NN + tx + 16*j] = acc[i][j] * scale;
}

// ------------------------------------------------- softmax + head-mix in place
// block per (b,n). Per-wave softmax (wave w owns heads 2w,2w+1 — no block
// barriers inside softmax), then head-mix with W[g,h], write mixed (pre-BN)
// rows back in place, emit BN partial sums (no atomics).
__global__ __launch_bounds__(256) void k_softmix(float* __restrict__ attn,
    const float* __restrict__ wmix_g, const float* __restrict__ bias_g,
    float* __restrict__ partial)
{
    const int bn = blockIdx.x;
    const int b = bn >> 10, n = bn & 1023;
    const int t = threadIdx.x, lane = t & 63, wid = t >> 6;
    __shared__ __align__(16) float row[8][1024];
    __shared__ float wmix[64];
    __shared__ float bsh[8];
    __shared__ float redsum[32], redsq[32];

    if (t < 64) wmix[t] = wmix_g[t];
    if (t >= 64 && t < 72) bsh[t - 64] = bias_g[t - 64];
    for (int h = 0; h < 8; ++h) {
        const float4* src = reinterpret_cast<const float4*>(
            attn + (((size_t)b*8 + h)*NN + n)*NN);
        reinterpret_cast<float4*>(row[h])[t] = src[t];
    }
    __syncthreads();

    // wave-local softmax: wave `wid` owns heads 2*wid and 2*wid+1
    for (int hh = 0; hh < 2; ++hh) {
        const int h = wid * 2 + hh;
        float vals[16];
        float lm = -1e30f;
        #pragma unroll
        for (int j = 0; j < 16; ++j) {
            vals[j] = row[h][lane + 64*j];
            lm = fmaxf(lm, vals[j]);
        }
        #pragma unroll
        for (int off = 32; off > 0; off >>= 1)
            lm = fmaxf(lm, __shfl_xor(lm, off));
        float ls = 0.f;
        #pragma unroll
        for (int j = 0; j < 16; ++j) {
            float e = __expf(vals[j] - lm);
            vals[j] = e;
            ls += e;
        }
        #pragma unroll
        for (int off = 32; off > 0; off >>= 1)
            ls += __shfl_xor(ls, off);
        const float inv = 1.f / ls;
        #pragma unroll
        for (int j = 0; j < 16; ++j)
            row[h][lane + 64*j] = vals[j] * inv;
    }
    __syncthreads();

    float sum_l[8], sq_l[8];
    for (int g = 0; g < 8; ++g) { sum_l[g] = 0.f; sq_l[g] = 0.f; }
    for (int mc = 0; mc < 4; ++mc) {
        int m = mc*256 + t;
        float a[8];
        for (int h = 0; h < 8; ++h) a[h] = row[h][m];
        for (int g = 0; g < 8; ++g) {
            float mix = bsh[g];
            for (int h = 0; h < 8; ++h) mix = fmaf(wmix[g*8 + h], a[h], mix);
            attn[(((size_t)b*8 + g)*NN + n)*NN + m] = mix;
            sum_l[g] += mix;
            sq_l[g] = fmaf(mix, mix, sq_l[g]);
        }
    }
    for (int g = 0; g < 8; ++g) {
        float s = sum_l[g], s2 = sq_l[g];
        for (int off = 32; off > 0; off >>= 1) {
            s  += __shfl_down(s,  off);
            s2 += __shfl_down(s2, off);
        }
        if (lane == 0) { redsum[g*4 + wid] = s; redsq[g*4 + wid] = s2; }
    }
    __syncthreads();
    if (t < 8) {
        partial[(size_t)t*8192 + bn] =
            redsum[t*4] + redsum[t*4+1] + redsum[t*4+2] + redsum[t*4+3];
        partial[(size_t)(8 + t)*8192 + bn] =
            redsq[t*4] + redsq[t*4+1] + redsq[t*4+2] + redsq[t*4+3];
    }
}

// ------------------------------------------------------------- BN scale/shift
__global__ __launch_bounds__(256) void k_bnprep(const float* __restrict__ partial,
    const float* __restrict__ gamma, const float* __restrict__ beta,
    float* __restrict__ stats)
{
    const int t = threadIdx.x, lane = t & 63, wid = t >> 6;
    __shared__ float tot[16];
    __shared__ float red[4];
    for (int g = 0; g < 16; ++g) {
        float s = 0.f;
        for (int j = 0; j < 32; ++j) s += partial[(size_t)g*8192 + t + 256*j];
        for (int off = 32; off > 0; off >>= 1) s += __shfl_down(s, off);
        if (lane == 0) red[wid] = s;
        __syncthreads();
        if (t == 0) tot[g] = red[0] + red[1] + red[2] + red[3];
        __syncthreads();
    }
    if (t < 8) {
        const float count = 8388608.0f;   // B*N*N
        float mean = tot[t] / count;
        float var = tot[8 + t] / count - mean * mean;   // biased
        float sc = gamma[t] * rsqrtf(var + BN_EPS);
        stats[16 + t] = sc;
        stats[24 + t] = beta[t] - mean * sc;
    }
}

// --------------------------------------- attn(BN'd inline) @ V, + writeback
// grid (8 ntile, 8 h, 8 b); Tn=128, BK=64. Fused-adjacent BN RMW (R1-proven
// minimal HBM traffic: load/BN/store in the same instruction neighborhood).
// 4-row micro-tile: thread = (dg = t>>5 of 12 d-cols, l = t&31 of 4 n-rows
// l, l+32, l+64, l+96) -> 48 acc. Per k-step: 48 FMA (96 VALU cyc/wave) vs
// 4 b32 + 3 b128 LDS (~59 cyc) — VALU-dominant, unlike the old 2-row tile
// where LDS pipe matched VALU 1:1 and capped VALUBusy at ~32%.
__global__ __launch_bounds__(256) void k_attnv(float* __restrict__ attn,
    const float* __restrict__ v, const float* __restrict__ stats,
    float* __restrict__ o)
{
    const int nt = blockIdx.x, h = blockIdx.y, b = blockIdx.z;
    const int t = threadIdx.x;
    const int l = t & 31, dg = t >> 5;
    __shared__ float As[128][65];    // 33.3 KB; col reads: bank (row+mi)%32, conflict-free
    __shared__ float Vs[64][100];    // 25.6 KB; pad 100: float4-aligned rows
    const float sc = stats[16 + h], sh = stats[24 + h];
    const int n0 = nt * 128;
    float* attn_b = attn + (((size_t)b*8 + h)*NN + n0)*NN;
    const float* v_b = v + (size_t)b*NN*NC + (size_t)h*ND;

    float acc[4][12];
    #pragma unroll
    for (int i = 0; i < 4; ++i)
        #pragma unroll
        for (int j = 0; j < 12; ++j) acc[i][j] = 0.f;

    for (int m0 = 0; m0 < 1024; m0 += 64) {
        // stage A tile (128x64): adjacent RMW (load -> BN -> store), LDS write
        #pragma unroll
        for (int j = 0; j < 8; ++j) {
            int idx4 = t + 256*j;
            int row = idx4 >> 4, c4 = idx4 & 15;
            float4* gp = reinterpret_cast<float4*>(attn_b + (size_t)row*NN + m0 + c4*4);
            float4 av = *gp;
            av.x = fmaf(av.x, sc, sh); av.y = fmaf(av.y, sc, sh);
            av.z = fmaf(av.z, sc, sh); av.w = fmaf(av.w, sc, sh);
            *gp = av;
            As[row][c4*4+0] = av.x; As[row][c4*4+1] = av.y;
            As[row][c4*4+2] = av.z; As[row][c4*4+3] = av.w;
        }
        // stage V tile (64 x 96)
        #pragma unroll
        for (int j = 0; j < 6; ++j) {
            int idx4 = t + 256*j;
            int row = idx4 / 24, c4 = idx4 - row*24;
            float4 vv = *reinterpret_cast<const float4*>(
                v_b + (size_t)(m0 + row)*NC + c4*4);
            *reinterpret_cast<float4*>(&Vs[row][c4*4]) = vv;
        }
        __syncthreads();
        #pragma unroll 4
        for (int mi = 0; mi < 64; ++mi) {
            float4 v0 = *reinterpret_cast<const float4*>(&Vs[mi][dg*12]);
            float4 v1 = *reinterpret_cast<const float4*>(&Vs[mi][dg*12 + 4]);
            float4 v2 = *reinterpret_cast<const float4*>(&Vs[mi][dg*12 + 8]);
            float a0 = As[l][mi],      a1 = As[l + 32][mi];
            float a2 = As[l + 64][mi], a3 = As[l + 96][mi];
            acc[0][0]=fmaf(a0,v0.x,acc[0][0]); acc[0][1]=fmaf(a0,v0.y,acc[0][1]);
            acc[0][2]=fmaf(a0,v0.z,acc[0][2]); acc[0][3]=fmaf(a0,v0.w,acc[0][3]);
            acc[0][4]=fmaf(a0,v1.x,acc[0][4]); acc[0][5]=fmaf(a0,v1.y,acc[0][5]);
            acc[0][6]=fmaf(a0,v1.z,acc[0][6]); acc[0][7]=fmaf(a0,v1.w,acc[0][7]);
            acc[0][8]=fmaf(a0,v2.x,acc[0][8]); acc[0][9]=fmaf(a0,v2.y,acc[0][9]);
            acc[0][10]=fmaf(a0,v2.z,acc[0][10]); acc[0][11]=fmaf(a0,v2.w,acc[0][11]);
            acc[1][0]=fmaf(a1,v0.x,acc[1][0]); acc[1][1]=fmaf(a1,v0.y,acc[1][1]);
            acc[1][2]=fmaf(a1,v0.z,acc[1][2]); acc[1][3]=fmaf(a1,v0.w,acc[1][3]);
            acc[1][4]=fmaf(a1,v1.x,acc[1][4]); acc[1][5]=fmaf(a1,v1.y,acc[1][5]);
            acc[1][6]=fmaf(a1,v1.z,acc[1][6]); acc[1][7]=fmaf(a1,v1.w,acc[1][7]);
            acc[1][8]=fmaf(a1,v2.x,acc[1][8]); acc[1][9]=fmaf(a1,v2.y,acc[1][9]);
            acc[1][10]=fmaf(a1,v2.z,acc[1][10]); acc[1][11]=fmaf(a1,v2.w,acc[1][11]);
            acc[2][0]=fmaf(a2,v0.x,acc[2][0]); acc[2][1]=fmaf(a2,v0.y,acc[2][1]);
            acc[2][2]=fmaf(a2,v0.z,acc[2][2]); acc[2][3]=fmaf(a2,v0.w,acc[2][3]);
            acc[2][4]=fmaf(a2,v1.x,acc[2][4]); acc[2][5]=fmaf(a2,v1.y,acc[2][5]);
            acc[2][6]=fmaf(a2,v1.z,acc[2][6]); acc[2][7]=fmaf(a2,v1.w,acc[2][7]);
            acc[2][8]=fmaf(a2,v2.x,acc[2][8]); acc[2][9]=fmaf(a2,v2.y,acc[2][9]);
            acc[2][10]=fmaf(a2,v2.z,acc[2][10]); acc[2][11]=fmaf(a2,v2.w,acc[2][11]);
            acc[3][0]=fmaf(a3,v0.x,acc[3][0]); acc[3][1]=fmaf(a3,v0.y,acc[3][1]);
            acc[3][2]=fmaf(a3,v0.z,acc[3][2]); acc[3][3]=fmaf(a3,v0.w,acc[3][3]);
            acc[3][4]=fmaf(a3,v1.x,acc[3][4]); acc[3][5]=fmaf(a3,v1.y,acc[3][5]);
            acc[3][6]=fmaf(a3,v1.z,acc[3][6]); acc[3][7]=fmaf(a3,v1.w,acc[3][7]);
            acc[3][8]=fmaf(a3,v2.x,acc[3][8]); acc[3][9]=fmaf(a3,v2.y,acc[3][9]);
            acc[3][10]=fmaf(a3,v2.z,acc[3][10]); acc[3][11]=fmaf(a3,v2.w,acc[3][11]);
        }
        __syncthreads();
    }
    // write rows n0+l+32r, d-range dg*12..dg*12+11
    #pragma unroll
    for (int r = 0; r < 4; ++r) {
        float* orow = o + ((size_t)b*NN + n0 + l + 32*r)*NC + (size_t)h*ND + dg*12;
        *reinterpret_cast<float4*>(orow+0) = make_float4(acc[r][0],acc[r][1],acc[r][2],acc[r][3]);
        *reinterpret_cast<float4*>(orow+4) = make_float4(acc[r][4],acc[r][5],acc[r][6],acc[r][7]);
        *reinterpret_cast<float4*>(orow+8) = make_float4(acc[r][8],acc[r][9],acc[r][10],acc[r][11]);
    }
}

// --------------------------------------------------------------- final proj
// out2[r,c'] = sum_k a[r,k] * W[c',k] + b[c']
// 64x64 block tile, BK=64, 4x4 micro-tile/thread, float4 LDS fragment reads.
// grid (12 c'-tiles, 128 r-tiles), 256 threads.
#define PROJ_DOT(i,j,av,bv) \
    acc[i][j]=fmaf(av.x,bv.x,acc[i][j]); acc[i][j]=fmaf(av.y,bv.y,acc[i][j]); \
    acc[i][j]=fmaf(av.z,bv.z,acc[i][j]); acc[i][j]=fmaf(av.w,bv.w,acc[i][j]);

__global__ __launch_bounds__(256) void k_proj(const float* __restrict__ a,
    const float* __restrict__ w, const float* __restrict__ bias,
    float* __restrict__ out)
{
    const int ct = blockIdx.x, rt = blockIdx.y;
    const int t = threadIdx.x;
    const int tx = t & 15, ty = t >> 4;
    __shared__ float As[64][68];     // 68: float4-aligned pad, 2-way max conflict
    __shared__ float Ws[64][68];
    const int r0 = rt * 64, c0 = ct * 64;
    float acc[4][4];
    #pragma unroll
    for (int i = 0; i < 4; ++i)
        #pragma unroll
        for (int j = 0; j < 4; ++j) acc[i][j] = 0.f;

    for (int k0 = 0; k0 < 768; k0 += 64) {
        // stage A (64 rows x 64 k) and W (64 cols x 64 k); 4 float4 each
        #pragma unroll
        for (int j = 0; j < 4; ++j) {
            int idx4 = t + 256*j;
            int row = idx4 >> 4, c4 = idx4 & 15;
            float4 av = *reinterpret_cast<const float4*>(
                a + (size_t)(r0 + row)*NC + k0 + c4*4);
            float4 wv = *reinterpret_cast<const float4*>(
                w + (size_t)(c0 + row)*NC + k0 + c4*4);
            *reinterpret_cast<float4*>(&As[row][c4*4]) = av;
            *reinterpret_cast<float4*>(&Ws[row][c4*4]) = wv;
        }
        __syncthreads();
        #pragma unroll 4
        for (int kk = 0; kk < 64; kk += 4) {
            float4 a0 = *reinterpret_cast<const float4*>(&As[ty     ][kk]);
            float4 a1 = *reinterpret_cast<const float4*>(&As[ty + 16][kk]);
            float4 a2 = *reinterpret_cast<const float4*>(&As[ty + 32][kk]);
            float4 a3 = *reinterpret_cast<const float4*>(&As[ty + 48][kk]);
            float4 b0 = *reinterpret_cast<const float4*>(&Ws[tx     ][kk]);
            float4 b1 = *reinterpret_cast<const float4*>(&Ws[tx + 16][kk]);
            float4 b2 = *reinterpret_cast<const float4*>(&Ws[tx + 32][kk]);
            float4 b3 = *reinterpret_cast<const float4*>(&Ws[tx + 48][kk]);
            PROJ_DOT(0,0,a0,b0) PROJ_DOT(0,1,a0,b1) PROJ_DOT(0,2,a0,b2) PROJ_DOT(0,3,a0,b3)
            PROJ_DOT(1,0,a1,b0) PROJ_DOT(1,1,a1,b1) PROJ_DOT(1,2,a1,b2) PROJ_DOT(1,3,a1,b3)
            PROJ_DOT(2,0,a2,b0) PROJ_DOT(2,1,a2,b1) PROJ_DOT(2,2,a2,b2) PROJ_DOT(2,3,a2,b3)
            PROJ_DOT(3,0,a3,b0) PROJ_DOT(3,1,a3,b1) PROJ_DOT(3,2,a3,b2) PROJ_DOT(3,3,a3,b3)
        }
        __syncthreads();
    }
    #pragma unroll
    for (int i = 0; i < 4; ++i) {
        float* orow = out + (size_t)(r0 + ty + 16*i)*NC + c0;
        #pragma unroll
        for (int j = 0; j < 4; ++j)
            orow[tx + 16*j] = acc[i][j] + bias[c0 + tx + 16*j];
    }
}

// ------------------------------------------------------------------- launcher
extern "C" void kernel_launch(void* const* d_in, const int* in_sizes, int n_in,
                              void* d_out, int out_size, void* d_ws, size_t ws_size,
                              hipStream_t stream)
{
    const float* x     = (const float*)d_in[0];
    const float* wq    = (const float*)d_in[1];
    const float* wk    = (const float*)d_in[2];
    const float* wv    = (const float*)d_in[3];
    const float* rw    = (const float*)d_in[4];   // (H,H,1,1)
    const float* rb    = (const float*)d_in[5];
    const float* gamma = (const float*)d_in[6];
    const float* beta  = (const float*)d_in[7];
    const float* pw    = (const float*)d_in[8];
    const float* pb    = (const float*)d_in[9];

    float* out  = (float*)d_out;                  // 6,291,456
    float* attn = out + (size_t)NB*NN*NC;         // 67,108,864

    float* ws      = (float*)d_ws;
    float* q       = ws;
    float* k       = ws + (size_t) 6291456;
    float* v       = ws + (size_t)12582912;
    float* o5      = ws + (size_t)18874368;
    float* partial = ws + (size_t)25165824;       // 16*8192
    float* stats   = ws + (size_t)25296896;       // 32

    k_conv   <<<8192, 256, 0, stream>>>(x, wq, wk, wv, q, k, v);
    k_qk     <<<dim3(16, 16, 64), 256, 0, stream>>>(q, k, attn);
    k_softmix<<<8192, 256, 0, stream>>>(attn, rw, rb, partial);
    k_bnprep <<<1, 256, 0, stream>>>(partial, gamma, beta, stats);
    k_attnv  <<<dim3(8, 8, 8), 256, 0, stream>>>(attn, v, stats, o5);
    k_proj   <<<dim3(12, 128), 256, 0, stream>>>(o5, pw, pb, out);
}

// Round 5
// 1078.701 us; speedup vs baseline: 1.1704x; 1.0445x over previous
//
#include <hip/hip_runtime.h>
#include <math.h>

// ReAttention: B=8, N=1024, C=768, H=8, d=96, s=16.
// d_out = [ out (8*1024*768) | attn_postBN (8*8*1024*1024) ]
// ws    = [ q | k | v | o5 (attn@V, B,N,C) | partial(16*8192) | stats(32) ] floats

#define NB    8
#define NN    1024
#define NC    768
#define NH    8
#define ND    96
#define BN_EPS 1e-5f

// ---------------------------------------------------------------- conv (q,k,v)
__global__ __launch_bounds__(256) void k_conv(const float* __restrict__ x,
    const float* __restrict__ wq, const float* __restrict__ wk,
    const float* __restrict__ wv,
    float* __restrict__ q, float* __restrict__ k, float* __restrict__ v)
{
    const int token = blockIdx.x;          // b*N+n, 8192 blocks
    const int t = threadIdx.x;             // 256 = one pixel each
    __shared__ float img[768];
    __shared__ float wsm[3][81];
    const float* xb = x + (size_t)token * 768;
    for (int i = t; i < 768; i += 256) img[i] = xb[i];
    if (t < 81) { wsm[0][t] = wq[t]; wsm[1][t] = wk[t]; wsm[2][t] = wv[t]; }
    __syncthreads();
    const int r = t >> 4, c = t & 15;
    float* outs[3] = { q, k, v };
    for (int cv = 0; cv < 3; ++cv) {
        for (int o = 0; o < 3; ++o) {
            float acc = 0.f;
            for (int i = 0; i < 3; ++i)
                for (int dr = 0; dr < 3; ++dr) {
                    int rr = r + dr - 1;
                    if (rr < 0 || rr > 15) continue;
                    for (int dc = 0; dc < 3; ++dc) {
                        int cc = c + dc - 1;
                        if (cc < 0 || cc > 15) continue;
                        acc = fmaf(img[i*256 + rr*16 + cc],
                                   wsm[cv][(o*3 + i)*9 + dr*3 + dc], acc);
                    }
                }
            outs[cv][(size_t)token*768 + o*256 + t] = acc;
        }
    }
}

// ---------------------------------------------------------------- Q K^T logits
// grid (16 mtile, 16 ntile, 64 bh); 64x64 C-tile, K=96 fully staged.
// float4 fragment reads along k (ds_read_b128): 8 b128 per 4-k-step for
// 64 FMA -> VALU-dominant (LDS ~96 cyc vs VALU 128 cyc per wave).
// Row stride 100 floats: 16B-aligned, B-frag 2-way bank alias (free),
// A-frag broadcast, disjoint spans. Scale folded into Q staging.
#define QK_DOT(i,j,av,bv) \
    acc[i][j]=fmaf(av.x,bv.x,acc[i][j]); acc[i][j]=fmaf(av.y,bv.y,acc[i][j]); \
    acc[i][j]=fmaf(av.z,bv.z,acc[i][j]); acc[i][j]=fmaf(av.w,bv.w,acc[i][j]);

__global__ __launch_bounds__(256) void k_qk(const float* __restrict__ q,
    const float* __restrict__ k, float* __restrict__ s_out)
{
    const int mt = blockIdx.x, nt = blockIdx.y, bh = blockIdx.z;
    const int b = bh >> 3, h = bh & 7;
    const int t = threadIdx.x;
    const int tx = t & 15, ty = t >> 4;
    __shared__ float Qs[64][100];
    __shared__ float Ks[64][100];
    const int n0 = nt * 64, m0 = mt * 64;
    const float* qb = q + ((size_t)b*NN + n0)*NC + h*ND;
    const float* kb = k + ((size_t)b*NN + m0)*NC + h*ND;
    const float scale = rsqrtf(96.0f);
    #pragma unroll
    for (int j = 0; j < 6; ++j) {               // 1536 float4 per matrix
        int idx4 = t + 256*j;
        int row = idx4 / 24, c4 = idx4 - row*24;
        float4 qv = *reinterpret_cast<const float4*>(qb + (size_t)row*NC + c4*4);
        float4 kv = *reinterpret_cast<const float4*>(kb + (size_t)row*NC + c4*4);
        qv.x *= scale; qv.y *= scale; qv.z *= scale; qv.w *= scale;
        *reinterpret_cast<float4*>(&Qs[row][c4*4]) = qv;
        *reinterpret_cast<float4*>(&Ks[row][c4*4]) = kv;
    }
    __syncthreads();
    float acc[4][4];
    #pragma unroll
    for (int i = 0; i < 4; ++i)
        #pragma unroll
        for (int j = 0; j < 4; ++j) acc[i][j] = 0.f;
    #pragma unroll 6
    for (int kk = 0; kk < 96; kk += 4) {
        float4 a0 = *reinterpret_cast<const float4*>(&Qs[ty     ][kk]);
        float4 a1 = *reinterpret_cast<const float4*>(&Qs[ty + 16][kk]);
        float4 a2 = *reinterpret_cast<const float4*>(&Qs[ty + 32][kk]);
        float4 a3 = *reinterpret_cast<const float4*>(&Qs[ty + 48][kk]);
        float4 b0 = *reinterpret_cast<const float4*>(&Ks[tx     ][kk]);
        float4 b1 = *reinterpret_cast<const float4*>(&Ks[tx + 16][kk]);
        float4 b2 = *reinterpret_cast<const float4*>(&Ks[tx + 32][kk]);
        float4 b3 = *reinterpret_cast<const float4*>(&Ks[tx + 48][kk]);
        QK_DOT(0,0,a0,b0) QK_DOT(0,1,a0,b1) QK_DOT(0,2,a0,b2) QK_DOT(0,3,a0,b3)
        QK_DOT(1,0,a1,b0) QK_DOT(1,1,a1,b1) QK_DOT(1,2,a1,b2) QK_DOT(1,3,a1,b3)
        QK_DOT(2,0,a2,b0) QK_DOT(2,1,a2,b1) QK_DOT(2,2,a2,b2) QK_DOT(2,3,a2,b3)
        QK_DOT(3,0,a3,b0) QK_DOT(3,1,a3,b1) QK_DOT(3,2,a3,b2) QK_DOT(3,3,a3,b3)
    }
    float* srow = s_out + ((size_t)bh*NN + n0)*NN + m0;
    #pragma unroll
    for (int i = 0; i < 4; ++i)
        #pragma unroll
        for (int j = 0; j < 4; ++j)
            srow[(size_t)(ty + 16*i)*NN + tx + 16*j] = acc[i][j];
}

// ------------------------------------------------- softmax + head-mix in place
// block per (b,n). Per-wave softmax (wave w owns heads 2w,2w+1 — no block
// barriers inside softmax), then head-mix with W[g,h], write mixed (pre-BN)
// rows back in place, emit BN partial sums (no atomics).
__global__ __launch_bounds__(256) void k_softmix(float* __restrict__ attn,
    const float* __restrict__ wmix_g, const float* __restrict__ bias_g,
    float* __restrict__ partial)
{
    const int bn = blockIdx.x;
    const int b = bn >> 10, n = bn & 1023;
    const int t = threadIdx.x, lane = t & 63, wid = t >> 6;
    __shared__ __align__(16) float row[8][1024];
    __shared__ float wmix[64];
    __shared__ float bsh[8];
    __shared__ float redsum[32], redsq[32];

    if (t < 64) wmix[t] = wmix_g[t];
    if (t >= 64 && t < 72) bsh[t - 64] = bias_g[t - 64];
    for (int h = 0; h < 8; ++h) {
        const float4* src = reinterpret_cast<const float4*>(
            attn + (((size_t)b*8 + h)*NN + n)*NN);
        reinterpret_cast<float4*>(row[h])[t] = src[t];
    }
    __syncthreads();

    // wave-local softmax: wave `wid` owns heads 2*wid and 2*wid+1
    for (int hh = 0; hh < 2; ++hh) {
        const int h = wid * 2 + hh;
        float vals[16];
        float lm = -1e30f;
        #pragma unroll
        for (int j = 0; j < 16; ++j) {
            vals[j] = row[h][lane + 64*j];
            lm = fmaxf(lm, vals[j]);
        }
        #pragma unroll
        for (int off = 32; off > 0; off >>= 1)
            lm = fmaxf(lm, __shfl_xor(lm, off));
        float ls = 0.f;
        #pragma unroll
        for (int j = 0; j < 16; ++j) {
            float e = __expf(vals[j] - lm);
            vals[j] = e;
            ls += e;
        }
        #pragma unroll
        for (int off = 32; off > 0; off >>= 1)
            ls += __shfl_xor(ls, off);
        const float inv = 1.f / ls;
        #pragma unroll
        for (int j = 0; j < 16; ++j)
            row[h][lane + 64*j] = vals[j] * inv;
    }
    __syncthreads();

    float sum_l[8], sq_l[8];
    for (int g = 0; g < 8; ++g) { sum_l[g] = 0.f; sq_l[g] = 0.f; }
    for (int mc = 0; mc < 4; ++mc) {
        int m = mc*256 + t;
        float a[8];
        for (int h = 0; h < 8; ++h) a[h] = row[h][m];
        for (int g = 0; g < 8; ++g) {
            float mix = bsh[g];
            for (int h = 0; h < 8; ++h) mix = fmaf(wmix[g*8 + h], a[h], mix);
            attn[(((size_t)b*8 + g)*NN + n)*NN + m] = mix;
            sum_l[g] += mix;
            sq_l[g] = fmaf(mix, mix, sq_l[g]);
        }
    }
    for (int g = 0; g < 8; ++g) {
        float s = sum_l[g], s2 = sq_l[g];
        for (int off = 32; off > 0; off >>= 1) {
            s  += __shfl_down(s,  off);
            s2 += __shfl_down(s2, off);
        }
        if (lane == 0) { redsum[g*4 + wid] = s; redsq[g*4 + wid] = s2; }
    }
    __syncthreads();
    if (t < 8) {
        partial[(size_t)t*8192 + bn] =
            redsum[t*4] + redsum[t*4+1] + redsum[t*4+2] + redsum[t*4+3];
        partial[(size_t)(8 + t)*8192 + bn] =
            redsq[t*4] + redsq[t*4+1] + redsq[t*4+2] + redsq[t*4+3];
    }
}

// ------------------------------------------------------------- BN scale/shift
__global__ __launch_bounds__(256) void k_bnprep(const float* __restrict__ partial,
    const float* __restrict__ gamma, const float* __restrict__ beta,
    float* __restrict__ stats)
{
    const int t = threadIdx.x, lane = t & 63, wid = t >> 6;
    __shared__ float tot[16];
    __shared__ float red[4];
    for (int g = 0; g < 16; ++g) {
        float s = 0.f;
        for (int j = 0; j < 32; ++j) s += partial[(size_t)g*8192 + t + 256*j];
        for (int off = 32; off > 0; off >>= 1) s += __shfl_down(s, off);
        if (lane == 0) red[wid] = s;
        __syncthreads();
        if (t == 0) tot[g] = red[0] + red[1] + red[2] + red[3];
        __syncthreads();
    }
    if (t < 8) {
        const float count = 8388608.0f;   // B*N*N
        float mean = tot[t] / count;
        float var = tot[8 + t] / count - mean * mean;   // biased
        float sc = gamma[t] * rsqrtf(var + BN_EPS);
        stats[16 + t] = sc;
        stats[24 + t] = beta[t] - mean * sc;
    }
}

// --------------------------------------- attn(BN'd inline) @ V, + writeback
// grid (8 ntile, 8 h, 8 b); Tn=128, BK=64. Fused-adjacent BN RMW (R1-proven
// minimal HBM traffic). 4-row micro-tile -> 48 acc; VALU-dominant.
__global__ __launch_bounds__(256) void k_attnv(float* __restrict__ attn,
    const float* __restrict__ v, const float* __restrict__ stats,
    float* __restrict__ o)
{
    const int nt = blockIdx.x, h = blockIdx.y, b = blockIdx.z;
    const int t = threadIdx.x;
    const int l = t & 31, dg = t >> 5;
    __shared__ float As[128][65];    // 33.3 KB; col reads conflict-free
    __shared__ float Vs[64][100];    // 25.6 KB; pad 100: float4-aligned rows
    const float sc = stats[16 + h], sh = stats[24 + h];
    const int n0 = nt * 128;
    float* attn_b = attn + (((size_t)b*8 + h)*NN + n0)*NN;
    const float* v_b = v + (size_t)b*NN*NC + (size_t)h*ND;

    float acc[4][12];
    #pragma unroll
    for (int i = 0; i < 4; ++i)
        #pragma unroll
        for (int j = 0; j < 12; ++j) acc[i][j] = 0.f;

    for (int m0 = 0; m0 < 1024; m0 += 64) {
        // stage A tile (128x64): adjacent RMW (load -> BN -> store), LDS write
        #pragma unroll
        for (int j = 0; j < 8; ++j) {
            int idx4 = t + 256*j;
            int row = idx4 >> 4, c4 = idx4 & 15;
            float4* gp = reinterpret_cast<float4*>(attn_b + (size_t)row*NN + m0 + c4*4);
            float4 av = *gp;
            av.x = fmaf(av.x, sc, sh); av.y = fmaf(av.y, sc, sh);
            av.z = fmaf(av.z, sc, sh); av.w = fmaf(av.w, sc, sh);
            *gp = av;
            As[row][c4*4+0] = av.x; As[row][c4*4+1] = av.y;
            As[row][c4*4+2] = av.z; As[row][c4*4+3] = av.w;
        }
        // stage V tile (64 x 96)
        #pragma unroll
        for (int j = 0; j < 6; ++j) {
            int idx4 = t + 256*j;
            int row = idx4 / 24, c4 = idx4 - row*24;
            float4 vv = *reinterpret_cast<const float4*>(
                v_b + (size_t)(m0 + row)*NC + c4*4);
            *reinterpret_cast<float4*>(&Vs[row][c4*4]) = vv;
        }
        __syncthreads();
        #pragma unroll 4
        for (int mi = 0; mi < 64; ++mi) {
            float4 v0 = *reinterpret_cast<const float4*>(&Vs[mi][dg*12]);
            float4 v1 = *reinterpret_cast<const float4*>(&Vs[mi][dg*12 + 4]);
            float4 v2 = *reinterpret_cast<const float4*>(&Vs[mi][dg*12 + 8]);
            float a0 = As[l][mi],      a1 = As[l + 32][mi];
            float a2 = As[l + 64][mi], a3 = As[l + 96][mi];
            acc[0][0]=fmaf(a0,v0.x,acc[0][0]); acc[0][1]=fmaf(a0,v0.y,acc[0][1]);
            acc[0][2]=fmaf(a0,v0.z,acc[0][2]); acc[0][3]=fmaf(a0,v0.w,acc[0][3]);
            acc[0][4]=fmaf(a0,v1.x,acc[0][4]); acc[0][5]=fmaf(a0,v1.y,acc[0][5]);
            acc[0][6]=fmaf(a0,v1.z,acc[0][6]); acc[0][7]=fmaf(a0,v1.w,acc[0][7]);
            acc[0][8]=fmaf(a0,v2.x,acc[0][8]); acc[0][9]=fmaf(a0,v2.y,acc[0][9]);
            acc[0][10]=fmaf(a0,v2.z,acc[0][10]); acc[0][11]=fmaf(a0,v2.w,acc[0][11]);
            acc[1][0]=fmaf(a1,v0.x,acc[1][0]); acc[1][1]=fmaf(a1,v0.y,acc[1][1]);
            acc[1][2]=fmaf(a1,v0.z,acc[1][2]); acc[1][3]=fmaf(a1,v0.w,acc[1][3]);
            acc[1][4]=fmaf(a1,v1.x,acc[1][4]); acc[1][5]=fmaf(a1,v1.y,acc[1][5]);
            acc[1][6]=fmaf(a1,v1.z,acc[1][6]); acc[1][7]=fmaf(a1,v1.w,acc[1][7]);
            acc[1][8]=fmaf(a1,v2.x,acc[1][8]); acc[1][9]=fmaf(a1,v2.y,acc[1][9]);
            acc[1][10]=fmaf(a1,v2.z,acc[1][10]); acc[1][11]=fmaf(a1,v2.w,acc[1][11]);
            acc[2][0]=fmaf(a2,v0.x,acc[2][0]); acc[2][1]=fmaf(a2,v0.y,acc[2][1]);
            acc[2][2]=fmaf(a2,v0.z,acc[2][2]); acc[2][3]=fmaf(a2,v0.w,acc[2][3]);
            acc[2][4]=fmaf(a2,v1.x,acc[2][4]); acc[2][5]=fmaf(a2,v1.y,acc[2][5]);
            acc[2][6]=fmaf(a2,v1.z,acc[2][6]); acc[2][7]=fmaf(a2,v1.w,acc[2][7]);
            acc[2][8]=fmaf(a2,v2.x,acc[2][8]); acc[2][9]=fmaf(a2,v2.y,acc[2][9]);
            acc[2][10]=fmaf(a2,v2.z,acc[2][10]); acc[2][11]=fmaf(a2,v2.w,acc[2][11]);
            acc[3][0]=fmaf(a3,v0.x,acc[3][0]); acc[3][1]=fmaf(a3,v0.y,acc[3][1]);
            acc[3][2]=fmaf(a3,v0.z,acc[3][2]); acc[3][3]=fmaf(a3,v0.w,acc[3][3]);
            acc[3][4]=fmaf(a3,v1.x,acc[3][4]); acc[3][5]=fmaf(a3,v1.y,acc[3][5]);
            acc[3][6]=fmaf(a3,v1.z,acc[3][6]); acc[3][7]=fmaf(a3,v1.w,acc[3][7]);
            acc[3][8]=fmaf(a3,v2.x,acc[3][8]); acc[3][9]=fmaf(a3,v2.y,acc[3][9]);
            acc[3][10]=fmaf(a3,v2.z,acc[3][10]); acc[3][11]=fmaf(a3,v2.w,acc[3][11]);
        }
        __syncthreads();
    }
    // write rows n0+l+32r, d-range dg*12..dg*12+11
    #pragma unroll
    for (int r = 0; r < 4; ++r) {
        float* orow = o + ((size_t)b*NN + n0 + l + 32*r)*NC + (size_t)h*ND + dg*12;
        *reinterpret_cast<float4*>(orow+0) = make_float4(acc[r][0],acc[r][1],acc[r][2],acc[r][3]);
        *reinterpret_cast<float4*>(orow+4) = make_float4(acc[r][4],acc[r][5],acc[r][6],acc[r][7]);
        *reinterpret_cast<float4*>(orow+8) = make_float4(acc[r][8],acc[r][9],acc[r][10],acc[r][11]);
    }
}

// --------------------------------------------------------------- final proj
// out2[r,c'] = sum_k a[r,k] * W[c',k] + b[c']
// 64x64 block tile, BK=64, 4x4 micro-tile/thread, float4 LDS fragment reads.
// grid (12 c'-tiles, 128 r-tiles), 256 threads.
#define PROJ_DOT(i,j,av,bv) \
    acc[i][j]=fmaf(av.x,bv.x,acc[i][j]); acc[i][j]=fmaf(av.y,bv.y,acc[i][j]); \
    acc[i][j]=fmaf(av.z,bv.z,acc[i][j]); acc[i][j]=fmaf(av.w,bv.w,acc[i][j]);

__global__ __launch_bounds__(256) void k_proj(const float* __restrict__ a,
    const float* __restrict__ w, const float* __restrict__ bias,
    float* __restrict__ out)
{
    const int ct = blockIdx.x, rt = blockIdx.y;
    const int t = threadIdx.x;
    const int tx = t & 15, ty = t >> 4;
    __shared__ float As[64][68];     // 68: float4-aligned pad, 2-way max conflict
    __shared__ float Ws[64][68];
    const int r0 = rt * 64, c0 = ct * 64;
    float acc[4][4];
    #pragma unroll
    for (int i = 0; i < 4; ++i)
        #pragma unroll
        for (int j = 0; j < 4; ++j) acc[i][j] = 0.f;

    for (int k0 = 0; k0 < 768; k0 += 64) {
        // stage A (64 rows x 64 k) and W (64 cols x 64 k); 4 float4 each
        #pragma unroll
        for (int j = 0; j < 4; ++j) {
            int idx4 = t + 256*j;
            int row = idx4 >> 4, c4 = idx4 & 15;
            float4 av = *reinterpret_cast<const float4*>(
                a + (size_t)(r0 + row)*NC + k0 + c4*4);
            float4 wv = *reinterpret_cast<const float4*>(
                w + (size_t)(c0 + row)*NC + k0 + c4*4);
            *reinterpret_cast<float4*>(&As[row][c4*4]) = av;
            *reinterpret_cast<float4*>(&Ws[row][c4*4]) = wv;
        }
        __syncthreads();
        #pragma unroll 4
        for (int kk = 0; kk < 64; kk += 4) {
            float4 a0 = *reinterpret_cast<const float4*>(&As[ty     ][kk]);
            float4 a1 = *reinterpret_cast<const float4*>(&As[ty + 16][kk]);
            float4 a2 = *reinterpret_cast<const float4*>(&As[ty + 32][kk]);
            float4 a3 = *reinterpret_cast<const float4*>(&As[ty + 48][kk]);
            float4 b0 = *reinterpret_cast<const float4*>(&Ws[tx     ][kk]);
            float4 b1 = *reinterpret_cast<const float4*>(&Ws[tx + 16][kk]);
            float4 b2 = *reinterpret_cast<const float4*>(&Ws[tx + 32][kk]);
            float4 b3 = *reinterpret_cast<const float4*>(&Ws[tx + 48][kk]);
            PROJ_DOT(0,0,a0,b0) PROJ_DOT(0,1,a0,b1) PROJ_DOT(0,2,a0,b2) PROJ_DOT(0,3,a0,b3)
            PROJ_DOT(1,0,a1,b0) PROJ_DOT(1,1,a1,b1) PROJ_DOT(1,2,a1,b2) PROJ_DOT(1,3,a1,b3)
            PROJ_DOT(2,0,a2,b0) PROJ_DOT(2,1,a2,b1) PROJ_DOT(2,2,a2,b2) PROJ_DOT(2,3,a2,b3)
            PROJ_DOT(3,0,a3,b0) PROJ_DOT(3,1,a3,b1) PROJ_DOT(3,2,a3,b2) PROJ_DOT(3,3,a3,b3)
        }
        __syncthreads();
    }
    #pragma unroll
    for (int i = 0; i < 4; ++i) {
        float* orow = out + (size_t)(r0 + ty + 16*i)*NC + c0;
        #pragma unroll
        for (int j = 0; j < 4; ++j)
            orow[tx + 16*j] = acc[i][j] + bias[c0 + tx + 16*j];
    }
}

// ------------------------------------------------------------------- launcher
extern "C" void kernel_launch(void* const* d_in, const int* in_sizes, int n_in,
                              void* d_out, int out_size, void* d_ws, size_t ws_size,
                              hipStream_t stream)
{
    const float* x     = (const float*)d_in[0];
    const float* wq    = (const float*)d_in[1];
    const float* wk    = (const float*)d_in[2];
    const float* wv    = (const float*)d_in[3];
    const float* rw    = (const float*)d_in[4];   // (H,H,1,1)
    const float* rb    = (const float*)d_in[5];
    const float* gamma = (const float*)d_in[6];
    const float* beta  = (const float*)d_in[7];
    const float* pw    = (const float*)d_in[8];
    const float* pb    = (const float*)d_in[9];

    float* out  = (float*)d_out;                  // 6,291,456
    float* attn = out + (size_t)NB*NN*NC;         // 67,108,864

    float* ws      = (float*)d_ws;
    float* q       = ws;
    float* k       = ws + (size_t) 6291456;
    float* v       = ws + (size_t)12582912;
    float* o5      = ws + (size_t)18874368;
    float* partial = ws + (size_t)25165824;       // 16*8192
    float* stats   = ws + (size_t)25296896;       // 32

    k_conv   <<<8192, 256, 0, stream>>>(x, wq, wk, wv, q, k, v);
    k_qk     <<<dim3(16, 16, 64), 256, 0, stream>>>(q, k, attn);
    k_softmix<<<8192, 256, 0, stream>>>(attn, rw, rb, partial);
    k_bnprep <<<1, 256, 0, stream>>>(partial, gamma, beta, stats);
    k_attnv  <<<dim3(8, 8, 8), 256, 0, stream>>>(attn, v, stats, o5);
    k_proj   <<<dim3(12, 128), 256, 0, stream>>>(o5, pw, pb, out);
}